// Round 1
// baseline (1354.229 us; speedup 1.0000x reference)
//
#include <hip/hip_runtime.h>
#include <math.h>

#define BB 512
#define NN 16
#define CC 256
#define KK 8192
#define BNC (BB*NN*CC)

typedef unsigned short u16;
typedef __attribute__((ext_vector_type(8))) short bf16x8;
typedef __attribute__((ext_vector_type(4))) float f32x4;

__device__ __forceinline__ u16 f2bf(float x) {
    unsigned u = __float_as_uint(x);
    unsigned r = (u + 0x7fffu + ((u >> 16) & 1u)) >> 16;
    return (u16)r;
}

__device__ __forceinline__ void gl2lds16(const void* g, void* l) {
    __builtin_amdgcn_global_load_lds(
        (const __attribute__((address_space(1))) void*)g,
        (__attribute__((address_space(3))) void*)l,
        16, 0, 0);
}

// ---------------------------------------------------------------------------
// stores 0.5*|e|^2 (folded into MFMA acc init in dist kernel)
__global__ void esq_kernel(const float* __restrict__ emb, float* __restrict__ e_sq) {
    int gid  = blockIdx.x * blockDim.x + threadIdx.x;
    int wave = gid >> 6;
    int lane = gid & 63;
    const float4 v = *(const float4*)(emb + (size_t)wave * CC + lane * 4);
    float s = v.x*v.x + v.y*v.y + v.z*v.z + v.w*v.w;
    #pragma unroll
    for (int m = 32; m >= 1; m >>= 1) s += __shfl_xor(s, m, 64);
    if (lane == 0) e_sq[wave] = 0.5f * s;
}

// stores NEGATED emb in bf16 so MFMA accumulates 0.5*esq - dot
__global__ void cvt_emb_kernel(const float* __restrict__ emb, u16* __restrict__ out) {
    int gid = blockIdx.x * blockDim.x + threadIdx.x;
    float4 v = ((const float4*)emb)[gid];
    ushort4 o;
    o.x = f2bf(-v.x); o.y = f2bf(-v.y); o.z = f2bf(-v.z); o.w = f2bf(-v.w);
    ((ushort4*)out)[gid] = o;
}

// initial pool for pn=1
__global__ void init_pool_kernel(const float* __restrict__ f,
                                 u16* __restrict__ rest_bf) {
    int b = blockIdx.x;
    int c = threadIdx.x;
    const float* base = f + (size_t)b * NN * CC + c;
    float acc = 0.f;
    #pragma unroll
    for (int n = 0; n < NN; ++n) acc += base[(size_t)n * CC];
    rest_bf[(size_t)b * CC + c] = f2bf(acc * (1.0f / 16.0f));
}

// ---------------------------------------------------------------------------
__device__ __forceinline__ unsigned long long shfl_xor_u64(unsigned long long v, int m) {
    unsigned lo = (unsigned)v, hi = (unsigned)(v >> 32);
    lo = __shfl_xor(lo, m, 64);
    hi = __shfl_xor(hi, m, 64);
    return ((unsigned long long)hi << 32) | lo;
}

// Barrier-free MFMA distance+argmin, v2:
//  - A (64 rows x 256) staged once into LDS via global_load_lds with the
//    conflict-free granule swizzle; read 4x ds_read_b128 per K-chunk.
//  - B streamed DIRECTLY global->registers, wave-private, 4-deep pipeline
//    (prefetch 3 chunks ahead; compiler emits counted vmcnt). No LDS round
//    trip, no barriers, no manual vmcnt(0) drain in the main loop.
//  - acc initialized to 0.5*e_sq (B is negated), so acc ends as 0.5*d;
//    ordering & ties identical to d = esq - 2*dot.
__global__ __launch_bounds__(256, 2) void dist_mfma_kernel(
        const u16* __restrict__ A, const u16* __restrict__ Bm,
        const float* __restrict__ e_sq,
        unsigned long long* __restrict__ packed, int cpb) {
    __shared__ __align__(16) u16 sA[16384];   // 32 KB: 64 rows x 256 K, swizzled
    const int tid = threadIdx.x;
    const int w = tid >> 6, l = tid & 63;
    const int r0 = blockIdx.x * 64;
    const int c0 = blockIdx.y * cpb;
    const int ncb = cpb >> 8;
    const int arow = l & 15;     // row/col within 16-tile
    const int aq   = l >> 4;     // quad (k-granule selector)

    // ---- stage A once: slot s = row*32 + (g ^ (row&31)), 16B granules ----
    {
        const int phys = tid & 31;
        #pragma unroll
        for (int i = 0; i < 8; ++i) {
            int s = tid + 256 * i;
            int row = s >> 5;
            int g = phys ^ (row & 31);
            gl2lds16(A + (((size_t)(r0 + row)) << 8) + g * 8,
                     (char*)sA + (size_t)(w * 64 + 256 * i) * 16);
        }
    }

    // ---- B direct-to-reg: lane-constant base, chunk t -> imm-friendly offsets
    // chunk t (global over cb,kc): cb'=t>>3, kc'=t&7
    // addr(u16) = bbase + cb'*65536 + j*4096 + kc'*32
    const u16* bbase = Bm + (((size_t)(c0 + w * 64 + arow)) << 8) + aq * 8;
    const float* eb = e_sq + c0 + w * 64 + arow;
    const int tmax = ncb * 8 - 1;

    bf16x8 b[4][4];
    #define LOADB(buf_, t_) {                                                   \
        const u16* p_ = bbase + (((size_t)((t_) >> 3)) << 16) + (((t_) & 7) << 5); \
        b[buf_][0] = *(const bf16x8*)(p_);                                      \
        b[buf_][1] = *(const bf16x8*)(p_ + 4096);                               \
        b[buf_][2] = *(const bf16x8*)(p_ + 8192);                               \
        b[buf_][3] = *(const bf16x8*)(p_ + 12288); }

    LOADB(0, 0)
    LOADB(1, 1)
    LOADB(2, 2)

    float eq[4];
    #pragma unroll
    for (int j = 0; j < 4; ++j) eq[j] = eb[j * 16];

    float bestd[16];
    int   bestk[16];
    #pragma unroll
    for (int t = 0; t < 16; ++t) { bestd[t] = 1e30f; bestk[t] = 0; }

    __syncthreads();   // A staged & visible; only barrier in the kernel

    for (int cb = 0; cb < ncb; ++cb) {
        // acc init = 0.5*esq (per-code, same for all 4 r-slots and all i)
        f32x4 acc[4][4];
        #pragma unroll
        for (int j = 0; j < 4; ++j) {
            const f32x4 e = {eq[j], eq[j], eq[j], eq[j]};
            #pragma unroll
            for (int i = 0; i < 4; ++i) acc[i][j] = e;
        }
        // prefetch next cb's esq (consumed one cb later)
        if (cb + 1 < ncb) {
            #pragma unroll
            for (int j = 0; j < 4; ++j) eq[j] = eb[(cb + 1) * 256 + j * 16];
        }

        const int tb = cb * 8;
        #pragma unroll
        for (int kc = 0; kc < 8; ++kc) {
            // A fragments from LDS (conflict-free swizzle)
            bf16x8 a[4];
            #pragma unroll
            for (int t = 0; t < 4; ++t) {
                const int row = t * 16 + arow;
                const int phys = (kc * 4 + aq) ^ (row & 31);
                a[t] = *(const bf16x8*)(sA + row * 256 + phys * 8);
            }
            // prefetch chunk kc+3 (next cb's chunks near the tail; clamp at end)
            int tp = tb + kc + 3;
            if (tp > tmax) tp = tmax;
            LOADB((kc + 3) & 3, tp)
            #pragma unroll
            for (int i = 0; i < 4; ++i)
                #pragma unroll
                for (int j = 0; j < 4; ++j)
                    acc[i][j] = __builtin_amdgcn_mfma_f32_16x16x32_bf16(
                                    a[i], b[kc & 3][j], acc[i][j], 0, 0, 0);
        }

        // fold: acc already holds 0.5*d; no fmaf needed
        #pragma unroll
        for (int i = 0; i < 4; ++i)
            #pragma unroll
            for (int r = 0; r < 4; ++r) {
                const int slot = i * 4 + r;
                #pragma unroll
                for (int j = 0; j < 4; ++j) {
                    const float d = acc[i][j][r];
                    const int k = c0 + cb * 256 + w * 64 + j * 16 + arow;
                    if (d < bestd[slot]) { bestd[slot] = d; bestk[slot] = k; }
                }
            }
    }
    #undef LOADB

    // cross-lane merge (lanes sharing l>>4 hold same rows) + global merge
    #pragma unroll
    for (int t = 0; t < 16; ++t) {
        unsigned u = __float_as_uint(bestd[t]);
        u = (u & 0x80000000u) ? ~u : (u | 0x80000000u);
        unsigned long long p = ((unsigned long long)u << 32) | (unsigned)bestk[t];
        #pragma unroll
        for (int m = 1; m < 16; m <<= 1) {
            unsigned long long o = shfl_xor_u64(p, m);
            if (o < p) p = o;
        }
        if (arow == 0)
            atomicMin(&packed[r0 + (t >> 2) * 16 + aq * 4 + (t & 3)], p);
    }
}

// ---------------------------------------------------------------------------
// Fused: gather + upsample + f_hat/f_rest update + qlat partial + pool for pn+1.
__global__ void update_pool_kernel(const float* __restrict__ f,
                                   const float* __restrict__ emb,
                                   const unsigned long long* __restrict__ packed,
                                   float* __restrict__ f_rest,
                                   float* __restrict__ f_hat,
                                   float* __restrict__ slots,
                                   u16* __restrict__ rest_bf, int pn) {
    int b = blockIdx.x;
    int c = threadIdx.x;
    __shared__ int sk[NN];
    __shared__ float red[4];
    if (threadIdx.x < pn)
        sk[threadIdx.x] = (int)(unsigned)(packed[b * pn + threadIdx.x] & 0xffffffffull);
    __syncthreads();

    float fr[NN];
    float acc_sq = 0.f;
    #pragma unroll
    for (int n = 0; n < NN; ++n) {
        double pos = (n + 0.5) * ((double)pn / 16.0) - 0.5;
        if (pos < 0.0) pos = 0.0;
        int i0 = (int)floor(pos);
        if (i0 > pn - 1) i0 = pn - 1;
        int i1 = i0 + 1;
        if (i1 > pn - 1) i1 = pn - 1;
        double frac = pos - (double)i0;
        float w1 = (float)frac;
        float w0 = (float)(1.0 - frac);
        float h = w0 * emb[(size_t)sk[i0] * CC + c] + w1 * emb[(size_t)sk[i1] * CC + c];
        size_t off = ((size_t)b * NN + n) * CC + c;
        float fh = f_hat[off] + h;
        f_hat[off] = fh;
        float fre = f_rest[off] - h;
        f_rest[off] = fre;
        fr[n] = fre;
        float diff = fh - f[off];
        acc_sq += diff * diff;
    }

    int wv = threadIdx.x >> 6, ln = threadIdx.x & 63;
    #pragma unroll
    for (int m = 32; m >= 1; m >>= 1) acc_sq += __shfl_xor(acc_sq, m, 64);
    if (ln == 0) red[wv] = acc_sq;

    int pn2 = pn + 1;
    if (pn < NN) {
        for (int p = 0; p < pn2; ++p) {
            int s = (p * NN) / pn2;
            int e = ((p + 1) * NN + pn2 - 1) / pn2;
            float v = 0.f;
            for (int n = s; n < e; ++n) v += fr[n];
            v *= 1.0f / (float)(e - s);
            rest_bf[((size_t)(b * pn2 + p)) * CC + c] = f2bf(v);
        }
    }
    __syncthreads();
    if (threadIdx.x == 0)
        atomicAdd(&slots[b & 255], (red[0] + red[1]) + (red[2] + red[3]));
}

// ---------------------------------------------------------------------------
__global__ void final_kernel(const float* __restrict__ slots, float* __restrict__ out_scalars) {
    float v = slots[threadIdx.x];
    #pragma unroll
    for (int m = 32; m >= 1; m >>= 1) v += __shfl_xor(v, m, 64);
    __shared__ float red[4];
    int wv = threadIdx.x >> 6, ln = threadIdx.x & 63;
    if (ln == 0) red[wv] = v;
    __syncthreads();
    if (threadIdx.x == 0) {
        float S = (red[0] + red[1]) + (red[2] + red[3]);
        float qlat = S / (float)BNC / (float)NN;
        out_scalars[0] = 0.25f * qlat;   // commit
        out_scalars[1] = qlat;           // qlat
    }
}

// ---------------------------------------------------------------------------
extern "C" void kernel_launch(void* const* d_in, const int* in_sizes, int n_in,
                              void* d_out, int out_size, void* d_ws, size_t ws_size,
                              hipStream_t stream) {
    (void)in_sizes; (void)n_in; (void)out_size; (void)ws_size;
    const float* f   = (const float*)d_in[0];   // [B, N, C]
    const float* emb = (const float*)d_in[1];   // [K, C]
    float* out = (float*)d_out;                 // f_hat [B*N*C] + 2 scalars

    float* ws      = (float*)d_ws;
    float* f_rest  = ws;                                   // BNC floats
    float* r2_pad  = f_rest + BNC;                         // 8192 (unused, layout keep)
    float* e_sq    = r2_pad + BB * NN;                     // K
    float* slots   = e_sq + KK;                            // 256
    unsigned long long* packed_all = (unsigned long long*)(slots + 256);  // 512*136
    u16* rest_bf = (u16*)(packed_all + (size_t)BB * 136);  // 8192*256 bf16
    u16* emb_bf  = rest_bf + (size_t)BB * NN * CC;         // K*C bf16 (negated)

    float* f_hat = out;  // accumulate output in place

    hipMemsetAsync(out, 0, (size_t)BNC * sizeof(float), stream);
    hipMemcpyAsync(f_rest, f, (size_t)BNC * sizeof(float), hipMemcpyDeviceToDevice, stream);
    hipMemsetAsync(slots, 0, 256 * sizeof(float), stream);
    hipMemsetAsync(packed_all, 0xFF, (size_t)BB * 136 * sizeof(unsigned long long), stream);
    esq_kernel<<<KK / 4, 256, 0, stream>>>(emb, e_sq);
    cvt_emb_kernel<<<KK * CC / 4 / 256, 256, 0, stream>>>(emb, emb_bf);
    init_pool_kernel<<<BB, 256, 0, stream>>>(f, rest_bf);

    // codebook splits per pn: keep grid >= ~256 blocks, cpb >= 256
    static const int splits_tab[17] = {0,32,32,16,16,8,8,8,8,4,4,4,4,4,4,4,4};

    for (int pn = 1; pn <= NN; ++pn) {
        unsigned long long* packed = packed_all + (size_t)BB * (pn * (pn - 1) / 2);
        int splits = splits_tab[pn];
        int cpb = KK / splits;
        dim3 grid(BB * pn / 64, splits);
        dist_mfma_kernel<<<grid, 256, 0, stream>>>(rest_bf, emb_bf, e_sq, packed, cpb);
        update_pool_kernel<<<BB, 256, 0, stream>>>(f, emb, packed, f_rest, f_hat,
                                                   slots, rest_bf, pn);
    }
    final_kernel<<<1, 256, 0, stream>>>(slots, out + BNC);
}

// Round 2
// 1099.504 us; speedup vs baseline: 1.2317x; 1.2317x over previous
//
#include <hip/hip_runtime.h>
#include <math.h>

#define BB 512
#define NN 16
#define CC 256
#define KK 8192
#define BNC (BB*NN*CC)

typedef unsigned short u16;
typedef __attribute__((ext_vector_type(8))) short bf16x8;
typedef __attribute__((ext_vector_type(4))) float f32x4;

__device__ __forceinline__ u16 f2bf(float x) {
    unsigned u = __float_as_uint(x);
    unsigned r = (u + 0x7fffu + ((u >> 16) & 1u)) >> 16;
    return (u16)r;
}

__device__ __forceinline__ void gl2lds16(const void* g, void* l) {
    __builtin_amdgcn_global_load_lds(
        (const __attribute__((address_space(1))) void*)g,
        (__attribute__((address_space(3))) void*)l,
        16, 0, 0);
}

// ---------------------------------------------------------------------------
// stores 0.5*|e|^2 (folded into MFMA acc init in dist kernel)
__global__ void esq_kernel(const float* __restrict__ emb, float* __restrict__ e_sq) {
    int gid  = blockIdx.x * blockDim.x + threadIdx.x;
    int wave = gid >> 6;
    int lane = gid & 63;
    const float4 v = *(const float4*)(emb + (size_t)wave * CC + lane * 4);
    float s = v.x*v.x + v.y*v.y + v.z*v.z + v.w*v.w;
    #pragma unroll
    for (int m = 32; m >= 1; m >>= 1) s += __shfl_xor(s, m, 64);
    if (lane == 0) e_sq[wave] = 0.5f * s;
}

// stores NEGATED emb in bf16 so MFMA accumulates 0.5*esq - dot
__global__ void cvt_emb_kernel(const float* __restrict__ emb, u16* __restrict__ out) {
    int gid = blockIdx.x * blockDim.x + threadIdx.x;
    float4 v = ((const float4*)emb)[gid];
    ushort4 o;
    o.x = f2bf(-v.x); o.y = f2bf(-v.y); o.z = f2bf(-v.z); o.w = f2bf(-v.w);
    ((ushort4*)out)[gid] = o;
}

// initial pool for pn=1
__global__ void init_pool_kernel(const float* __restrict__ f,
                                 u16* __restrict__ rest_bf) {
    int b = blockIdx.x;
    int c = threadIdx.x;
    const float* base = f + (size_t)b * NN * CC + c;
    float acc = 0.f;
    #pragma unroll
    for (int n = 0; n < NN; ++n) acc += base[(size_t)n * CC];
    rest_bf[(size_t)b * CC + c] = f2bf(acc * (1.0f / 16.0f));
}

// ---------------------------------------------------------------------------
__device__ __forceinline__ unsigned long long shfl_xor_u64(unsigned long long v, int m) {
    unsigned lo = (unsigned)v, hi = (unsigned)(v >> 32);
    lo = __shfl_xor(lo, m, 64);
    hi = __shfl_xor(hi, m, 64);
    return ((unsigned long long)hi << 32) | lo;
}

// Barrier-free MFMA distance+argmin, v3 (swapped operands):
//  - f_rest rows (64 x 256) staged once into LDS (conflict-free granule
//    swizzle, proven 0-conflict), consumed as the MFMA **B** operand.
//  - codes (negated emb) stream global->registers as the MFMA **A** operand:
//    4 buffers, depth-3 prefetch (~3 MFMA phases > L2 latency), compiler
//    emits counted vmcnt. No LDS round trip for codes, no barriers in loop.
//  - C-row = code, C-col = f-row  =>  per lane only 4 f-rows (j) and 16
//    codes (i,r): bestd[4]/bestk[4] (vs 16) and e_sq acc-init is a plain
//    float4 vector load (code index aq*4+r == 16B-aligned float4).
//  - amdgpu_waves_per_eu(2,2) pins the allocator at 2 waves/EU (256 VGPR
//    budget) so it cannot spill to chase 4 waves/EU (v2's failure: 78 MB
//    of scratch WRITE_SIZE at VGPR_Count=128).
__global__ __attribute__((amdgpu_flat_work_group_size(256, 256)))
           __attribute__((amdgpu_waves_per_eu(2, 2)))
void dist_mfma_kernel(
        const u16* __restrict__ A, const u16* __restrict__ Bm,
        const float* __restrict__ e_sq,
        unsigned long long* __restrict__ packed, int cpb) {
    __shared__ __align__(16) u16 sA[16384];   // 32 KB: 64 rows x 256 K, swizzled
    const int tid = threadIdx.x;
    const int w = tid >> 6, l = tid & 63;
    const int r0 = blockIdx.x * 64;
    const int c0 = blockIdx.y * cpb;
    const int ncb = cpb >> 8;
    const int arow = l & 15;     // row/col within 16-tile
    const int aq   = l >> 4;     // quad (k-granule selector)

    // ---- stage f-rest rows once: slot s = row*32 + (g ^ (row&31)) ----
    {
        const int phys = tid & 31;
        #pragma unroll
        for (int i = 0; i < 8; ++i) {
            int s = tid + 256 * i;
            int row = s >> 5;
            int g = phys ^ (row & 31);
            gl2lds16(A + (((size_t)(r0 + row)) << 8) + g * 8,
                     (char*)sA + (size_t)(w * 64 + 256 * i) * 16);
        }
    }

    // ---- codes direct-to-reg. chunk t: cb'=t>>3, kc'=t&7
    // lane addr(u16) = cbase + cb'*65536 + i*4096 + kc'*32
    const u16* cbase = Bm + (((size_t)(c0 + w * 64 + arow)) << 8) + aq * 8;
    const float* ebase = e_sq + c0 + w * 64 + aq * 4;   // float4 base, i-stride 16
    const int tmax = ncb * 8 - 1;

    bf16x8 cf[4][4];
    #define LOADC(buf_, t_) {                                                   \
        const u16* p_ = cbase + (((size_t)((t_) >> 3)) << 16) + (((t_) & 7) << 5); \
        cf[buf_][0] = *(const bf16x8*)(p_);                                     \
        cf[buf_][1] = *(const bf16x8*)(p_ + 4096);                              \
        cf[buf_][2] = *(const bf16x8*)(p_ + 8192);                              \
        cf[buf_][3] = *(const bf16x8*)(p_ + 12288); }

    LOADC(0, 0)
    LOADC(1, 1)
    LOADC(2, 2)

    float4 eq[4];
    #pragma unroll
    for (int i = 0; i < 4; ++i) eq[i] = *(const float4*)(ebase + i * 16);

    float bestd[4];
    int   bestk[4];
    #pragma unroll
    for (int j = 0; j < 4; ++j) { bestd[j] = 1e30f; bestk[j] = 0; }

    __syncthreads();   // sA staged & visible; only barrier in the kernel

    for (int cb = 0; cb < ncb; ++cb) {
        // acc init = 0.5*esq per code (codes live on the row/reg axis)
        f32x4 acc[4][4];
        #pragma unroll
        for (int i = 0; i < 4; ++i) {
            const f32x4 e = {eq[i].x, eq[i].y, eq[i].z, eq[i].w};
            #pragma unroll
            for (int j = 0; j < 4; ++j) acc[i][j] = e;
        }
        // prefetch next cb's esq (consumed one cb later; clamp at end)
        {
            const int cbn = (cb + 1 < ncb) ? cb + 1 : cb;
            #pragma unroll
            for (int i = 0; i < 4; ++i)
                eq[i] = *(const float4*)(ebase + cbn * 256 + i * 16);
        }

        const int tb = cb * 8;
        #pragma unroll
        for (int kc = 0; kc < 8; ++kc) {
            // f-row fragments from LDS (conflict-free swizzle)
            bf16x8 b[4];
            #pragma unroll
            for (int j = 0; j < 4; ++j) {
                const int row = j * 16 + arow;
                const int phys = (kc * 4 + aq) ^ (row & 31);
                b[j] = *(const bf16x8*)(sA + row * 256 + phys * 8);
            }
            // prefetch chunk kc+3 into the buffer freed last iteration
            int tp = tb + kc + 3;
            if (tp > tmax) tp = tmax;
            LOADC((kc + 3) & 3, tp)
            #pragma unroll
            for (int i = 0; i < 4; ++i)
                #pragma unroll
                for (int j = 0; j < 4; ++j)
                    acc[i][j] = __builtin_amdgcn_mfma_f32_16x16x32_bf16(
                                    cf[kc & 3][i], b[j], acc[i][j], 0, 0, 0);
        }

        // fold: acc holds 0.5*d; argmin per f-row (j) over this cb's 16 codes
        #pragma unroll
        for (int i = 0; i < 4; ++i)
            #pragma unroll
            for (int r = 0; r < 4; ++r) {
                const int k = c0 + cb * 256 + w * 64 + i * 16 + aq * 4 + r;
                #pragma unroll
                for (int j = 0; j < 4; ++j) {
                    const float d = acc[i][j][r];
                    if (d < bestd[j]) { bestd[j] = d; bestk[j] = k; }
                }
            }
    }
    #undef LOADC

    // merge across the 4 aq-lanes holding the same f-row, then global merge
    #pragma unroll
    for (int j = 0; j < 4; ++j) {
        unsigned u = __float_as_uint(bestd[j]);
        u = (u & 0x80000000u) ? ~u : (u | 0x80000000u);
        unsigned long long p = ((unsigned long long)u << 32) | (unsigned)bestk[j];
        unsigned long long o = shfl_xor_u64(p, 16);
        if (o < p) p = o;
        o = shfl_xor_u64(p, 32);
        if (o < p) p = o;
        if (aq == 0)
            atomicMin(&packed[r0 + j * 16 + arow], p);
    }
}

// ---------------------------------------------------------------------------
// Fused: gather + upsample + f_hat/f_rest update + qlat partial + pool for pn+1.
__global__ void update_pool_kernel(const float* __restrict__ f,
                                   const float* __restrict__ emb,
                                   const unsigned long long* __restrict__ packed,
                                   float* __restrict__ f_rest,
                                   float* __restrict__ f_hat,
                                   float* __restrict__ slots,
                                   u16* __restrict__ rest_bf, int pn) {
    int b = blockIdx.x;
    int c = threadIdx.x;
    __shared__ int sk[NN];
    __shared__ float red[4];
    if (threadIdx.x < pn)
        sk[threadIdx.x] = (int)(unsigned)(packed[b * pn + threadIdx.x] & 0xffffffffull);
    __syncthreads();

    float fr[NN];
    float acc_sq = 0.f;
    #pragma unroll
    for (int n = 0; n < NN; ++n) {
        double pos = (n + 0.5) * ((double)pn / 16.0) - 0.5;
        if (pos < 0.0) pos = 0.0;
        int i0 = (int)floor(pos);
        if (i0 > pn - 1) i0 = pn - 1;
        int i1 = i0 + 1;
        if (i1 > pn - 1) i1 = pn - 1;
        double frac = pos - (double)i0;
        float w1 = (float)frac;
        float w0 = (float)(1.0 - frac);
        float h = w0 * emb[(size_t)sk[i0] * CC + c] + w1 * emb[(size_t)sk[i1] * CC + c];
        size_t off = ((size_t)b * NN + n) * CC + c;
        float fh = f_hat[off] + h;
        f_hat[off] = fh;
        float fre = f_rest[off] - h;
        f_rest[off] = fre;
        fr[n] = fre;
        float diff = fh - f[off];
        acc_sq += diff * diff;
    }

    int wv = threadIdx.x >> 6, ln = threadIdx.x & 63;
    #pragma unroll
    for (int m = 32; m >= 1; m >>= 1) acc_sq += __shfl_xor(acc_sq, m, 64);
    if (ln == 0) red[wv] = acc_sq;

    int pn2 = pn + 1;
    if (pn < NN) {
        for (int p = 0; p < pn2; ++p) {
            int s = (p * NN) / pn2;
            int e = ((p + 1) * NN + pn2 - 1) / pn2;
            float v = 0.f;
            for (int n = s; n < e; ++n) v += fr[n];
            v *= 1.0f / (float)(e - s);
            rest_bf[((size_t)(b * pn2 + p)) * CC + c] = f2bf(v);
        }
    }
    __syncthreads();
    if (threadIdx.x == 0)
        atomicAdd(&slots[b & 255], (red[0] + red[1]) + (red[2] + red[3]));
}

// ---------------------------------------------------------------------------
__global__ void final_kernel(const float* __restrict__ slots, float* __restrict__ out_scalars) {
    float v = slots[threadIdx.x];
    #pragma unroll
    for (int m = 32; m >= 1; m >>= 1) v += __shfl_xor(v, m, 64);
    __shared__ float red[4];
    int wv = threadIdx.x >> 6, ln = threadIdx.x & 63;
    if (ln == 0) red[wv] = v;
    __syncthreads();
    if (threadIdx.x == 0) {
        float S = (red[0] + red[1]) + (red[2] + red[3]);
        float qlat = S / (float)BNC / (float)NN;
        out_scalars[0] = 0.25f * qlat;   // commit
        out_scalars[1] = qlat;           // qlat
    }
}

// ---------------------------------------------------------------------------
extern "C" void kernel_launch(void* const* d_in, const int* in_sizes, int n_in,
                              void* d_out, int out_size, void* d_ws, size_t ws_size,
                              hipStream_t stream) {
    (void)in_sizes; (void)n_in; (void)out_size; (void)ws_size;
    const float* f   = (const float*)d_in[0];   // [B, N, C]
    const float* emb = (const float*)d_in[1];   // [K, C]
    float* out = (float*)d_out;                 // f_hat [B*N*C] + 2 scalars

    float* ws      = (float*)d_ws;
    float* f_rest  = ws;                                   // BNC floats
    float* r2_pad  = f_rest + BNC;                         // 8192 (unused, layout keep)
    float* e_sq    = r2_pad + BB * NN;                     // K (0.5*|e|^2)
    float* slots   = e_sq + KK;                            // 256
    unsigned long long* packed_all = (unsigned long long*)(slots + 256);  // 512*136
    u16* rest_bf = (u16*)(packed_all + (size_t)BB * 136);  // 8192*256 bf16
    u16* emb_bf  = rest_bf + (size_t)BB * NN * CC;         // K*C bf16 (negated)

    float* f_hat = out;  // accumulate output in place

    hipMemsetAsync(out, 0, (size_t)BNC * sizeof(float), stream);
    hipMemcpyAsync(f_rest, f, (size_t)BNC * sizeof(float), hipMemcpyDeviceToDevice, stream);
    hipMemsetAsync(slots, 0, 256 * sizeof(float), stream);
    hipMemsetAsync(packed_all, 0xFF, (size_t)BB * 136 * sizeof(unsigned long long), stream);
    esq_kernel<<<KK / 4, 256, 0, stream>>>(emb, e_sq);
    cvt_emb_kernel<<<KK * CC / 4 / 256, 256, 0, stream>>>(emb, emb_bf);
    init_pool_kernel<<<BB, 256, 0, stream>>>(f, rest_bf);

    // codebook splits per pn: keep grid >= ~256 blocks, cpb >= 256
    static const int splits_tab[17] = {0,32,32,16,16,8,8,8,8,4,4,4,4,4,4,4,4};

    for (int pn = 1; pn <= NN; ++pn) {
        unsigned long long* packed = packed_all + (size_t)BB * (pn * (pn - 1) / 2);
        int splits = splits_tab[pn];
        int cpb = KK / splits;
        dim3 grid(BB * pn / 64, splits);
        dist_mfma_kernel<<<grid, 256, 0, stream>>>(rest_bf, emb_bf, e_sq, packed, cpb);
        update_pool_kernel<<<BB, 256, 0, stream>>>(f, emb, packed, f_rest, f_hat,
                                                   slots, rest_bf, pn);
    }
    final_kernel<<<1, 256, 0, stream>>>(slots, out + BNC);
}

// Round 4
// 772.045 us; speedup vs baseline: 1.7541x; 1.4241x over previous
//
#include <hip/hip_runtime.h>
#include <math.h>

#define BB 512
#define NN 16
#define CC 256
#define KK 8192
#define BNC (BB*NN*CC)

typedef unsigned short u16;
typedef __attribute__((ext_vector_type(8))) short bf16x8;
typedef __attribute__((ext_vector_type(4))) float f32x4;

__device__ __forceinline__ u16 f2bf(float x) {
    unsigned u = __float_as_uint(x);
    unsigned r = (u + 0x7fffu + ((u >> 16) & 1u)) >> 16;
    return (u16)r;
}

__device__ __forceinline__ void gl2lds16(const void* g, void* l) {
    __builtin_amdgcn_global_load_lds(
        (const __attribute__((address_space(1))) void*)g,
        (__attribute__((address_space(3))) void*)l,
        16, 0, 0);
}

__device__ __forceinline__ void gl2lds4(const void* g, void* l) {
    __builtin_amdgcn_global_load_lds(
        (const __attribute__((address_space(1))) void*)g,
        (__attribute__((address_space(3))) void*)l,
        4, 0, 0);
}

// ---------------------------------------------------------------------------
// stores 0.5*|e|^2 (folded into MFMA acc init in dist kernel)
__global__ void esq_kernel(const float* __restrict__ emb, float* __restrict__ e_sq) {
    int gid  = blockIdx.x * blockDim.x + threadIdx.x;
    int wave = gid >> 6;
    int lane = gid & 63;
    const float4 v = *(const float4*)(emb + (size_t)wave * CC + lane * 4);
    float s = v.x*v.x + v.y*v.y + v.z*v.z + v.w*v.w;
    #pragma unroll
    for (int m = 32; m >= 1; m >>= 1) s += __shfl_xor(s, m, 64);
    if (lane == 0) e_sq[wave] = 0.5f * s;
}

// stores NEGATED emb in bf16 so MFMA accumulates 0.5*esq - dot
__global__ void cvt_emb_kernel(const float* __restrict__ emb, u16* __restrict__ out) {
    int gid = blockIdx.x * blockDim.x + threadIdx.x;
    float4 v = ((const float4*)emb)[gid];
    ushort4 o;
    o.x = f2bf(-v.x); o.y = f2bf(-v.y); o.z = f2bf(-v.z); o.w = f2bf(-v.w);
    ((ushort4*)out)[gid] = o;
}

// initial pool for pn=1
__global__ void init_pool_kernel(const float* __restrict__ f,
                                 u16* __restrict__ rest_bf) {
    int b = blockIdx.x;
    int c = threadIdx.x;
    const float* base = f + (size_t)b * NN * CC + c;
    float acc = 0.f;
    #pragma unroll
    for (int n = 0; n < NN; ++n) acc += base[(size_t)n * CC];
    rest_bf[(size_t)b * CC + c] = f2bf(acc * (1.0f / 16.0f));
}

// ---------------------------------------------------------------------------
__device__ __forceinline__ unsigned long long shfl_xor_u64(unsigned long long v, int m) {
    unsigned lo = (unsigned)v, hi = (unsigned)(v >> 32);
    lo = __shfl_xor(lo, m, 64);
    hi = __shfl_xor(hi, m, 64);
    return ((unsigned long long)hi << 32) | lo;
}

// Barrier-free MFMA distance+argmin, v5 (= v4 with constant-foldable waits):
//  - f_rest rows (64 x 256) loaded ONCE global->registers as resident MFMA
//    B fragments bf[4][8] (128 VGPRs). Zero LDS traffic for them in-loop.
//  - codes (negated emb) stream via global_load_lds (no data VGPRs) into a
//    wave-private 4-deep LDS ring (4KB/buf); consumed with COUNTED vmcnt
//    via literal inline-asm (vmcnt(8)/vmcnt(9), never 0): 3 chunks stay in
//    flight across phases. Only 4 ds_read_b128 per 16 MFMAs.
//  - 0.5*e_sq staged per-cb via 4B global_load_lds (double buffer) so the
//    vmcnt bookkeeping stays exact; acc init = f32x4 register copy.
//  - LDS = 66KB/block caps occupancy at 2 blocks/CU -> backend register
//    budget 256 (kills the spill-for-occupancy failure of v2/v3).
//  - no __syncthreads at all (all LDS wave-private).
__global__ __launch_bounds__(256, 2) void dist_mfma_kernel(
        const u16* __restrict__ A, const u16* __restrict__ Bm,
        const float* __restrict__ e_sq,
        unsigned long long* __restrict__ packed, int cpb) {
    __shared__ __align__(16) u16 sC[32768];   // 64KB: 4 waves x 4 bufs x (64 codes x 64B)
    __shared__ __align__(16) float sE[512];   // 2KB: 4 waves x 2 bufs x 64 esq
    const int tid = threadIdx.x;
    const int w = tid >> 6, l = tid & 63;
    const int r0 = blockIdx.x * 64;
    const int c0 = blockIdx.y * cpb;
    const int ncb = cpb >> 8;
    const int tmax = ncb * 8 - 1;
    const int arow = l & 15;     // row/col within 16-tile
    const int aq   = l >> 4;     // quad (k-granule selector)

    // ---- resident f-row fragments: bf[j][kc] = row (r0+j*16+arow), granule (kc*4+aq)
    bf16x8 bf[4][8];
    {
        const u16* fb = A + (((size_t)(r0 + arow)) << 8) + aq * 8;
        #pragma unroll
        for (int j = 0; j < 4; ++j)
            #pragma unroll
            for (int kc = 0; kc < 8; ++kc)
                bf[j][kc] = *(const bf16x8*)(fb + (j << 12) + (kc << 5));
    }

    // ---- code staging: chunk t (cb=t>>3, kc=t&7): 64 codes x 64B K-slice
    // LDS layout per buf: [code 0..63][4 x 16B granules], linear; wave reads
    // it as one contiguous 1KB region per i-tile -> conflict-free.
    const int loff = ((l >> 2) << 8) + ((l & 3) << 3);   // u16: code(l>>2)*256 + g(l&3)*8
    const u16* Pb = Bm + (((size_t)(c0 + w * 64)) << 8) + loff;
    char* ldsc = (char*)sC + (w << 14);                  // wave's 16KB ring
    const float* ebuf = sE + (w << 7);                   // wave's 2x64 esq

    #define STAGEC(t_, buf_) { \
        const int tt_ = ((t_) > tmax) ? tmax : (t_); \
        const u16* s_ = Pb + (((size_t)(tt_ >> 3)) << 16) + ((tt_ & 7) << 5); \
        char* d_ = ldsc + ((buf_) << 12); \
        gl2lds16(s_,          d_); \
        gl2lds16(s_ + 4096,   d_ + 1024); \
        gl2lds16(s_ + 8192,   d_ + 2048); \
        gl2lds16(s_ + 12288,  d_ + 3072); }

    #define STAGEE(cb_) { \
        const int cc_ = ((cb_) >= ncb) ? (ncb - 1) : (cb_); \
        gl2lds4(e_sq + c0 + cc_ * 256 + w * 64 + l, \
                (char*)sE + ((((w << 1) | ((cb_) & 1))) << 8)); }

    // prologue: esq(cb0) then chunks 0,1,2  (13 vm loads outstanding)
    STAGEE(0)
    STAGEC(0, 0) STAGEC(1, 1) STAGEC(2, 2)

    float bestd[4];
    int   bestk[4];
    #pragma unroll
    for (int j = 0; j < 4; ++j) { bestd[j] = 1e30f; bestk[j] = 0; }

    for (int cb = 0; cb < ncb; ++cb) {
        f32x4 acc[4][4];
        const int tb = cb * 8;
        #pragma unroll
        for (int kc = 0; kc < 8; ++kc) {
            // Counted wait for chunk t's staging (issue order per cb:
            // ..., C(t), C(t+1), C(t+2), then kc0 issues C(t+3), E(cb+1), ...).
            // Newer-than-needed outstanding loads: 8, except at kc=1..3 where
            // the esq stage (issued between C-chunks at kc0) adds one -> 9.
            if (kc >= 1 && kc <= 3) {
                asm volatile("s_waitcnt vmcnt(9)" ::: "memory");
            } else {
                asm volatile("s_waitcnt vmcnt(8)" ::: "memory");
            }
            if (kc == 0) {
                // esq for this cb (staged one cb ago; retired by the wait above)
                f32x4 eqv[4];
                #pragma unroll
                for (int i = 0; i < 4; ++i)
                    eqv[i] = *(const f32x4*)(ebuf + ((cb & 1) << 6) + i * 16 + (aq << 2));
                #pragma unroll
                for (int i = 0; i < 4; ++i)
                    #pragma unroll
                    for (int j = 0; j < 4; ++j) acc[i][j] = eqv[i];
            }
            const int t = tb + kc;
            bf16x8 cf[4];
            const u16* cbp = (const u16*)(ldsc + ((t & 3) << 12));
            #pragma unroll
            for (int i = 0; i < 4; ++i)
                cf[i] = *(const bf16x8*)(cbp + ((i * 16 + arow) << 5) + (aq << 3));
            STAGEC(t + 3, (t + 3) & 3)
            if (kc == 0) STAGEE(cb + 1)
            #pragma unroll
            for (int i = 0; i < 4; ++i)
                #pragma unroll
                for (int j = 0; j < 4; ++j)
                    acc[i][j] = __builtin_amdgcn_mfma_f32_16x16x32_bf16(
                                    cf[i], bf[j][kc], acc[i][j], 0, 0, 0);
        }

        // fold: acc holds 0.5*d; argmin per f-row (j) over this cb's 16 codes/lane
        #pragma unroll
        for (int i = 0; i < 4; ++i)
            #pragma unroll
            for (int r = 0; r < 4; ++r) {
                const int k = c0 + cb * 256 + w * 64 + i * 16 + (aq << 2) + r;
                #pragma unroll
                for (int j = 0; j < 4; ++j) {
                    const float d = acc[i][j][r];
                    if (d < bestd[j]) { bestd[j] = d; bestk[j] = k; }
                }
            }
    }
    #undef STAGEC
    #undef STAGEE

    // merge across the 4 aq-lanes holding the same f-row, then global merge
    #pragma unroll
    for (int j = 0; j < 4; ++j) {
        unsigned u = __float_as_uint(bestd[j]);
        u = (u & 0x80000000u) ? ~u : (u | 0x80000000u);
        unsigned long long p = ((unsigned long long)u << 32) | (unsigned)bestk[j];
        unsigned long long o = shfl_xor_u64(p, 16);
        if (o < p) p = o;
        o = shfl_xor_u64(p, 32);
        if (o < p) p = o;
        if (aq == 0)
            atomicMin(&packed[r0 + j * 16 + arow], p);
    }
}

// ---------------------------------------------------------------------------
// Fused: gather + upsample + f_hat/f_rest update + qlat partial + pool for pn+1.
__global__ void update_pool_kernel(const float* __restrict__ f,
                                   const float* __restrict__ emb,
                                   const unsigned long long* __restrict__ packed,
                                   float* __restrict__ f_rest,
                                   float* __restrict__ f_hat,
                                   float* __restrict__ slots,
                                   u16* __restrict__ rest_bf, int pn) {
    int b = blockIdx.x;
    int c = threadIdx.x;
    __shared__ int sk[NN];
    __shared__ float red[4];
    if (threadIdx.x < pn)
        sk[threadIdx.x] = (int)(unsigned)(packed[b * pn + threadIdx.x] & 0xffffffffull);
    __syncthreads();

    float fr[NN];
    float acc_sq = 0.f;
    #pragma unroll
    for (int n = 0; n < NN; ++n) {
        double pos = (n + 0.5) * ((double)pn / 16.0) - 0.5;
        if (pos < 0.0) pos = 0.0;
        int i0 = (int)floor(pos);
        if (i0 > pn - 1) i0 = pn - 1;
        int i1 = i0 + 1;
        if (i1 > pn - 1) i1 = pn - 1;
        double frac = pos - (double)i0;
        float w1 = (float)frac;
        float w0 = (float)(1.0 - frac);
        float h = w0 * emb[(size_t)sk[i0] * CC + c] + w1 * emb[(size_t)sk[i1] * CC + c];
        size_t off = ((size_t)b * NN + n) * CC + c;
        float fh = f_hat[off] + h;
        f_hat[off] = fh;
        float fre = f_rest[off] - h;
        f_rest[off] = fre;
        fr[n] = fre;
        float diff = fh - f[off];
        acc_sq += diff * diff;
    }

    int wv = threadIdx.x >> 6, ln = threadIdx.x & 63;
    #pragma unroll
    for (int m = 32; m >= 1; m >>= 1) acc_sq += __shfl_xor(acc_sq, m, 64);
    if (ln == 0) red[wv] = acc_sq;

    int pn2 = pn + 1;
    if (pn < NN) {
        for (int p = 0; p < pn2; ++p) {
            int s = (p * NN) / pn2;
            int e = ((p + 1) * NN + pn2 - 1) / pn2;
            float v = 0.f;
            for (int n = s; n < e; ++n) v += fr[n];
            v *= 1.0f / (float)(e - s);
            rest_bf[((size_t)(b * pn2 + p)) * CC + c] = f2bf(v);
        }
    }
    __syncthreads();
    if (threadIdx.x == 0)
        atomicAdd(&slots[b & 255], (red[0] + red[1]) + (red[2] + red[3]));
}

// ---------------------------------------------------------------------------
__global__ void final_kernel(const float* __restrict__ slots, float* __restrict__ out_scalars) {
    float v = slots[threadIdx.x];
    #pragma unroll
    for (int m = 32; m >= 1; m >>= 1) v += __shfl_xor(v, m, 64);
    __shared__ float red[4];
    int wv = threadIdx.x >> 6, ln = threadIdx.x & 63;
    if (ln == 0) red[wv] = v;
    __syncthreads();
    if (threadIdx.x == 0) {
        float S = (red[0] + red[1]) + (red[2] + red[3]);
        float qlat = S / (float)BNC / (float)NN;
        out_scalars[0] = 0.25f * qlat;   // commit
        out_scalars[1] = qlat;           // qlat
    }
}

// ---------------------------------------------------------------------------
extern "C" void kernel_launch(void* const* d_in, const int* in_sizes, int n_in,
                              void* d_out, int out_size, void* d_ws, size_t ws_size,
                              hipStream_t stream) {
    (void)in_sizes; (void)n_in; (void)out_size; (void)ws_size;
    const float* f   = (const float*)d_in[0];   // [B, N, C]
    const float* emb = (const float*)d_in[1];   // [K, C]
    float* out = (float*)d_out;                 // f_hat [B*N*C] + 2 scalars

    float* ws      = (float*)d_ws;
    float* f_rest  = ws;                                   // BNC floats
    float* r2_pad  = f_rest + BNC;                         // 8192 (unused, layout keep)
    float* e_sq    = r2_pad + BB * NN;                     // K (0.5*|e|^2)
    float* slots   = e_sq + KK;                            // 256
    unsigned long long* packed_all = (unsigned long long*)(slots + 256);  // 512*136
    u16* rest_bf = (u16*)(packed_all + (size_t)BB * 136);  // 8192*256 bf16
    u16* emb_bf  = rest_bf + (size_t)BB * NN * CC;         // K*C bf16 (negated)

    float* f_hat = out;  // accumulate output in place

    hipMemsetAsync(out, 0, (size_t)BNC * sizeof(float), stream);
    hipMemcpyAsync(f_rest, f, (size_t)BNC * sizeof(float), hipMemcpyDeviceToDevice, stream);
    hipMemsetAsync(slots, 0, 256 * sizeof(float), stream);
    hipMemsetAsync(packed_all, 0xFF, (size_t)BB * 136 * sizeof(unsigned long long), stream);
    esq_kernel<<<KK / 4, 256, 0, stream>>>(emb, e_sq);
    cvt_emb_kernel<<<KK * CC / 4 / 256, 256, 0, stream>>>(emb, emb_bf);
    init_pool_kernel<<<BB, 256, 0, stream>>>(f, rest_bf);

    // codebook splits per pn: keep grid >= ~256 blocks, cpb >= 256
    static const int splits_tab[17] = {0,32,32,16,16,8,8,8,8,4,4,4,4,4,4,4,4};

    for (int pn = 1; pn <= NN; ++pn) {
        unsigned long long* packed = packed_all + (size_t)BB * (pn * (pn - 1) / 2);
        int splits = splits_tab[pn];
        int cpb = KK / splits;
        dim3 grid(BB * pn / 64, splits);
        dist_mfma_kernel<<<grid, 256, 0, stream>>>(rest_bf, emb_bf, e_sq, packed, cpb);
        update_pool_kernel<<<BB, 256, 0, stream>>>(f, emb, packed, f_rest, f_hat,
                                                   slots, rest_bf, pn);
    }
    final_kernel<<<1, 256, 0, stream>>>(slots, out + BNC);
}